// Round 2
// baseline (270.973 us; speedup 1.0000x reference)
//
#include <hip/hip_runtime.h>
#include <hip/hip_bf16.h>

// fUpModule CG tensor product, MAXL=5, TAUS=OUT_TAUS=8, BATCH=1024, fp32 I/O.
// Pipeline per launch: cg_init (CG table -> ws), w_init (W/(std+eps) -> ws),
// fup_main (1 block / batch row).

constexpr int NTRIP = 69;
constexpr int NL    = 6;
constexpr int BATCH = 1024;
constexpr int ROW   = 288;     // complex elements per activation/output row
constexpr int MID_LDS = 4224;  // float2 slots for mid buffer (66*64)

struct Meta {
    int tl1[NTRIP], tl2[NTRIP], tll[NTRIP];
    int tf1[NTRIP], tf2[NTRIP];   // complex offsets of F[l1], F[l2] blocks
    int ttloc[NTRIP];             // T start of this triple within its l group
    int tcg[NTRIP];               // offset into dense CG table
    int trip_of_l[NL][16];
    int ntrips[NL];
    int mid_tau[NL], std_off[NL], w_off[NL], f_l[NL];
    int cg_total;
};

constexpr Meta build_meta() {
    Meta m{};
    int fl[NL] = {};
    {
        int acc = 0;
        for (int l = 0; l < NL; l++) { fl[l] = acc; m.f_l[l] = acc; acc += 8 * (2 * l + 1); }
    }
    int idx = 0, cgo = 0;
    for (int l1 = 0; l1 <= 5; l1++)
        for (int l2 = 0; l2 <= l1; l2++) {
            int lmax = (l1 + l2 < 5) ? (l1 + l2) : 5;
            for (int l = l1 - l2; l <= lmax; l++) {
                m.tl1[idx] = l1; m.tl2[idx] = l2; m.tll[idx] = l;
                m.tf1[idx] = fl[l1]; m.tf2[idx] = fl[l2];
                m.ttloc[idx] = 64 * m.ntrips[l];
                m.trip_of_l[l][m.ntrips[l]] = idx;
                m.ntrips[l]++;
                m.tcg[idx] = cgo;
                cgo += (2 * l + 1) * (2 * l1 + 1) * (2 * l2 + 1);
                idx++;
            }
        }
    m.cg_total = cgo;
    int so = 0, wo = 0;
    for (int l = 0; l < NL; l++) {
        m.mid_tau[l] = 64 * m.ntrips[l];
        m.std_off[l] = so; so += m.mid_tau[l];
        m.w_off[l]   = wo; wo += 8 * m.mid_tau[l];
    }
    return m;
}

constexpr Meta MT = build_meta();
static_assert(MT.cg_total == 24367, "cg table size");
constexpr int CG_TOTAL = MT.cg_total;
constexpr int CG_PAD   = 24368;  // 8B-aligned float count
constexpr int WLEN     = 35328;  // complex weights
static_assert(MT.w_off[5] + 8 * MT.mid_tau[5] == WLEN, "wlen");
static_assert(MT.std_off[5] + MT.mid_tau[5] == 4416, "stdlen");

// ---------------------------------------------------------------- CG init ---
__device__ __forceinline__ double dfact(int n) {
    double r = 1.0;
    for (int i = 2; i <= n; i++) r *= (double)i;
    return r;
}

__global__ void cg_init(float* __restrict__ cg) {
    int i = blockIdx.x * 256 + threadIdx.x;
    if (i >= CG_TOTAL) return;
    int trip = 0;
    for (int k = 1; k < NTRIP; k++) if (MT.tcg[k] <= i) trip = k;
    const int l1 = MT.tl1[trip], l2 = MT.tl2[trip], l = MT.tll[trip];
    const int n1 = 2 * l1 + 1, n2 = 2 * l2 + 1;
    int rel = i - MT.tcg[trip];
    int mi = rel / (n1 * n2);
    int r2 = rel - mi * n1 * n2;
    int ai = r2 / n2;
    int ci = r2 - ai * n2;
    int m = mi - l, m1 = ai - l1, m2 = ci - l2;
    float v = 0.f;
    if (m1 + m2 == m) {
        double pre = sqrt((double)(2 * l + 1) * dfact(l + l1 - l2) * dfact(l - l1 + l2) *
                          dfact(l1 + l2 - l) / dfact(l1 + l2 + l + 1));
        pre *= sqrt(dfact(l + m) * dfact(l - m) * dfact(l1 - m1) * dfact(l1 + m1) *
                    dfact(l2 - m2) * dfact(l2 + m2));
        double s = 0.0;
        for (int k = 0; k <= l1 + l2 - l; k++) {
            int d0 = k, d1 = l1 + l2 - l - k, d2 = l1 - m1 - k;
            int d3 = l2 + m2 - k, d4 = l - l2 + m1 + k, d5 = l - l1 - m2 + k;
            if (d0 < 0 || d1 < 0 || d2 < 0 || d3 < 0 || d4 < 0 || d5 < 0) continue;
            double den = dfact(d0) * dfact(d1) * dfact(d2) * dfact(d3) * dfact(d4) * dfact(d5);
            s += ((k & 1) ? -1.0 : 1.0) / den;
        }
        v = (float)(pre * s);
    }
    cg[i] = v;
}

// ------------------------------------------------------- weight / std fold --
__global__ void w_init(const float2* __restrict__ w,
                       const float* __restrict__ stdv,
                       float2* __restrict__ wp) {
    int i = blockIdx.x * 256 + threadIdx.x;
    if (i >= WLEN) return;
    int l = 0;
    for (int k = 1; k < NL; k++) if (MT.w_off[k] <= i) l = k;
    int rel = i - MT.w_off[l];
    int T = rel % MT.mid_tau[l];
    float inv = 1.0f / (stdv[MT.std_off[l] + T] + 1e-5f);
    float2 wv = w[i];
    wp[i] = make_float2(wv.x * inv, wv.y * inv);
}

// ------------------------------------------------------------- main kernel --
template <int L>
__device__ __forceinline__ void process_l(int b, int tid,
                                          const float2* __restrict__ F,
                                          float2* __restrict__ mid,
                                          const float* __restrict__ cg,
                                          const float2* __restrict__ wp,
                                          float2* __restrict__ out) {
    constexpr int TW  = 2 * L + 1;
    constexpr int NTL = MT.ntrips[L];
    constexpr int MAXSLOT = 66 / TW;                 // slots per LDS chunk
    constexpr int NCH = (NTL + MAXSLOT - 1) / MAXSLOT;
    constexpr int NT  = MT.mid_tau[L];
    static_assert(MAXSLOT * 64 * TW <= MID_LDS, "mid chunk fits");

    const int g = tid >> 5;      // output channel o (8 groups)
    const int lane = tid & 31;

    float2 accv[TW];
#pragma unroll
    for (int i = 0; i < TW; i++) accv[i] = make_float2(0.f, 0.f);

    for (int ch = 0; ch < NCH; ch++) {
        const int s0 = ch * MAXSLOT;
        const int s1 = (s0 + MAXSLOT < NTL) ? (s0 + MAXSLOT) : NTL;
        const int nslots = s1 - s0;
        __syncthreads();   // prev consumers of `mid` done (also covers F load)

        // ---- stage 1: mid[T, m] for triples in [s0, s1) -----------------
        const int items = nslots * 64;
        for (int it = tid; it < items; it += 256) {
            const int slot = s0 + (it >> 6);
            const int ts = it & 63;            // wave-uniform slot per 64 lanes
            const int trip = MT.trip_of_l[L][slot];
            const int l1 = MT.tl1[trip], l2 = MT.tl2[trip];
            const int n1 = 2 * l1 + 1, n2 = 2 * l2 + 1;
            const int t = ts >> 3, s = ts & 7;
            const float2* F1 = F + MT.tf1[trip] + t * n1;
            const float2* F2 = F + MT.tf2[trip] + s * n2;
            const float* C = cg + MT.tcg[trip];
            float2* md = mid + ((MT.ttloc[trip] - s0 * 64) + ts) * TW;
#pragma unroll
            for (int mi = 0; mi < TW; mi++) {
                const int base = mi - L;                 // m
                int lo = base + l1 - l2; lo = lo < 0 ? 0 : lo;
                int hi = base + l1 + l2; hi = hi > 2 * l1 ? 2 * l1 : hi;
                float re = 0.f, im = 0.f;
                const float* Cm = C + mi * n1 * n2;
                for (int ai = lo; ai <= hi; ai++) {
                    const int ci = base + l1 + l2 - ai;
                    const float cv = Cm[ai * n2 + ci];   // wave-uniform -> broadcast
                    const float2 a = F1[ai], c2 = F2[ci];
                    re = fmaf(cv, a.x * c2.x - a.y * c2.y, re);
                    im = fmaf(cv, a.x * c2.y + a.y * c2.x, im);
                }
                md[mi] = make_float2(re, im);
            }
        }
        __syncthreads();

        // ---- stage 2: out[o,m] += sum_T W'[o,T] * mid[T,m] --------------
        const float2* W = wp + MT.w_off[L] + g * NT;
        const int T0 = s0 * 64, T1 = s1 * 64;
        for (int T = T0 + lane; T < T1; T += 32) {
            const float2 w = W[T];
            const float2* md = mid + (T - T0) * TW;
#pragma unroll
            for (int mi = 0; mi < TW; mi++) {
                const float2 mv = md[mi];
                accv[mi].x = fmaf(w.x, mv.x, fmaf(-w.y, mv.y, accv[mi].x));
                accv[mi].y = fmaf(w.x, mv.y, fmaf(w.y, mv.x, accv[mi].y));
            }
        }
    }

    // 32-lane reduction within each o-group (stays inside half-wave)
#pragma unroll
    for (int off = 16; off >= 1; off >>= 1) {
#pragma unroll
        for (int mi = 0; mi < TW; mi++) {
            accv[mi].x += __shfl_xor(accv[mi].x, off, 64);
            accv[mi].y += __shfl_xor(accv[mi].y, off, 64);
        }
    }
    if (lane == 0) {
        float2* orow = out + (size_t)b * ROW + MT.f_l[L] + g * TW;
#pragma unroll
        for (int mi = 0; mi < TW; mi++) orow[mi] = accv[mi];
    }
}

__global__ __launch_bounds__(256) void fup_main(const float2* __restrict__ act,
                                               const float* __restrict__ cg,
                                               const float2* __restrict__ wp,
                                               float2* __restrict__ out) {
    __shared__ float2 F[ROW];
    __shared__ float2 mid[MID_LDS];
    const int b = blockIdx.x;
    const int tid = threadIdx.x;
    const float2* arow = act + (size_t)b * ROW;
    for (int i = tid; i < ROW; i += 256) F[i] = arow[i];
    // sync happens at top of first chunk inside process_l<0>
    process_l<0>(b, tid, F, mid, cg, wp, out);
    process_l<1>(b, tid, F, mid, cg, wp, out);
    process_l<2>(b, tid, F, mid, cg, wp, out);
    process_l<3>(b, tid, F, mid, cg, wp, out);
    process_l<4>(b, tid, F, mid, cg, wp, out);
    process_l<5>(b, tid, F, mid, cg, wp, out);
}

// ----------------------------------------------------------------- launch ---
extern "C" void kernel_launch(void* const* d_in, const int* in_sizes, int n_in,
                              void* d_out, int out_size, void* d_ws, size_t ws_size,
                              hipStream_t stream) {
    const float2* act  = (const float2*)d_in[0];
    const float2* wts  = (const float2*)d_in[1];
    const float*  stdv = (const float*)d_in[2];
    float2* out = (float2*)d_out;

    float*  cg = (float*)d_ws;                                    // 24368 floats
    float2* wp = (float2*)((char*)d_ws + (size_t)CG_PAD * 4);     // 35328 float2

    hipLaunchKernelGGL(cg_init, dim3((CG_TOTAL + 255) / 256), dim3(256), 0, stream, cg);
    hipLaunchKernelGGL(w_init,  dim3((WLEN + 255) / 256),     dim3(256), 0, stream,
                       wts, stdv, wp);
    hipLaunchKernelGGL(fup_main, dim3(BATCH), dim3(256), 0, stream, act, cg, wp, out);
}

// Round 3
// 137.832 us; speedup vs baseline: 1.9660x; 1.9660x over previous
//
#include <hip/hip_runtime.h>
#include <hip/hip_bf16.h>
#include <utility>

// fUpModule CG tensor product, MAXL=5, TAUS=OUT_TAUS=8, BATCH=1024, fp32 I/O.
// R3: fully compile-time-unrolled stage 1 (register F rows, scalar CG loads,
// static windows), transposed mid[m][T] + float4 stage 2, balanced wave split.

constexpr int NTRIP = 69;
constexpr int NL    = 6;
constexpr int BATCH = 1024;
constexpr int ROW   = 288;     // complex elements per activation/output row
constexpr int MID_LDS = 4224;  // float2 slots for mid buffer

struct Meta {
    int tl1[NTRIP], tl2[NTRIP], tll[NTRIP];
    int tf1[NTRIP], tf2[NTRIP];   // complex offsets of F[l1], F[l2] blocks
    int ttloc[NTRIP];             // T start of this triple within its l group
    int tcg[NTRIP];               // offset into dense CG table
    int trip_of_l[NL][16];
    int ntrips[NL];
    int mid_tau[NL], std_off[NL], w_off[NL], f_l[NL];
    int nch[NL];
    int ch_start[NL][2], ch_cnt[NL][2];
    int wave_of[NL][16];
    int cg_total;
};

constexpr Meta build_meta() {
    Meta m{};
    int fl[NL] = {};
    {
        int acc = 0;
        for (int l = 0; l < NL; l++) { fl[l] = acc; m.f_l[l] = acc; acc += 8 * (2 * l + 1); }
    }
    int idx = 0, cgo = 0;
    for (int l1 = 0; l1 <= 5; l1++)
        for (int l2 = 0; l2 <= l1; l2++) {
            int lmax = (l1 + l2 < 5) ? (l1 + l2) : 5;
            for (int l = l1 - l2; l <= lmax; l++) {
                m.tl1[idx] = l1; m.tl2[idx] = l2; m.tll[idx] = l;
                m.tf1[idx] = fl[l1]; m.tf2[idx] = fl[l2];
                m.ttloc[idx] = 64 * m.ntrips[l];
                m.trip_of_l[l][m.ntrips[l]] = idx;
                m.ntrips[l]++;
                m.tcg[idx] = cgo;
                cgo += (2 * l + 1) * (2 * l1 + 1) * (2 * l2 + 1);
                idx++;
            }
        }
    m.cg_total = cgo;
    int so = 0, wo = 0;
    for (int l = 0; l < NL; l++) {
        m.mid_tau[l] = 64 * m.ntrips[l];
        m.std_off[l] = so; so += m.mid_tau[l];
        m.w_off[l]   = wo; wo += 8 * m.mid_tau[l];
    }
    // chunking (balanced) + greedy cost-balanced slot->wave assignment
    for (int l = 0; l < NL; l++) {
        const int TW = 2 * l + 1;
        const int maxslot = MID_LDS / (64 * TW);
        const int ntl = m.ntrips[l];
        const int nch = (ntl + maxslot - 1) / maxslot;
        m.nch[l] = nch;
        int done = 0;
        for (int c = 0; c < nch; c++) {
            int cnt = (ntl - done + (nch - c) - 1) / (nch - c);
            m.ch_start[l][c] = done; m.ch_cnt[l][c] = cnt; done += cnt;
        }
        for (int c = 0; c < nch; c++) {
            const int s0 = m.ch_start[l][c], cnt = m.ch_cnt[l][c];
            int cost[16] = {}; bool asg[16] = {};
            for (int i = 0; i < cnt; i++) {
                int trip = m.trip_of_l[l][s0 + i];
                int l1 = m.tl1[trip], l2 = m.tl2[trip];
                int tc = 0;
                for (int mi = 0; mi < TW; mi++) {
                    int base = mi - l;
                    int lo = base + l1 - l2; if (lo < 0) lo = 0;
                    int hi = base + l1 + l2; if (hi > 2 * l1) hi = 2 * l1;
                    tc += hi - lo + 1;
                }
                cost[i] = tc * 6 + (2 * l1 + 1 + 2 * l2 + 1) * 2;
            }
            int load[4] = {};
            for (int k = 0; k < cnt; k++) {
                int best = -1, bc = -1;
                for (int i = 0; i < cnt; i++)
                    if (!asg[i] && cost[i] > bc) { bc = cost[i]; best = i; }
                asg[best] = true;
                int wsel = 0;
                for (int w2 = 1; w2 < 4; w2++) if (load[w2] < load[wsel]) wsel = w2;
                m.wave_of[l][s0 + best] = wsel;
                load[wsel] += bc;
            }
        }
    }
    return m;
}

constexpr Meta MT = build_meta();
static_assert(MT.cg_total == 24367, "cg table size");
constexpr int CG_TOTAL = MT.cg_total;
constexpr int WLEN     = 35328;  // complex weights
static_assert(MT.w_off[5] + 8 * MT.mid_tau[5] == WLEN, "wlen");
static_assert(MT.std_off[5] + MT.mid_tau[5] == 4416, "stdlen");

// compile-time for
template <int... Is, class F>
__device__ __forceinline__ void static_for_impl(std::integer_sequence<int, Is...>, F&& f) {
    (f(std::integral_constant<int, Is>{}), ...);
}
template <int N, class F>
__device__ __forceinline__ void static_for(F&& f) {
    static_for_impl(std::make_integer_sequence<int, N>{}, (F&&)f);
}

// ---------------------------------------------------------------- CG init ---
__device__ __forceinline__ double dfact(int n) {
    double r = 1.0;
    for (int i = 2; i <= n; i++) r *= (double)i;
    return r;
}

__global__ void cg_init(float* __restrict__ cg) {
    int i = blockIdx.x * 256 + threadIdx.x;
    if (i >= CG_TOTAL) return;
    int trip = 0;
    for (int k = 1; k < NTRIP; k++) if (MT.tcg[k] <= i) trip = k;
    const int l1 = MT.tl1[trip], l2 = MT.tl2[trip], l = MT.tll[trip];
    const int n1 = 2 * l1 + 1, n2 = 2 * l2 + 1;
    int rel = i - MT.tcg[trip];
    int mi = rel / (n1 * n2);
    int r2 = rel - mi * n1 * n2;
    int ai = r2 / n2;
    int ci = r2 - ai * n2;
    int m = mi - l, m1 = ai - l1, m2 = ci - l2;
    float v = 0.f;
    if (m1 + m2 == m) {
        double pre = sqrt((double)(2 * l + 1) * dfact(l + l1 - l2) * dfact(l - l1 + l2) *
                          dfact(l1 + l2 - l) / dfact(l1 + l2 + l + 1));
        pre *= sqrt(dfact(l + m) * dfact(l - m) * dfact(l1 - m1) * dfact(l1 + m1) *
                    dfact(l2 - m2) * dfact(l2 + m2));
        double s = 0.0;
        for (int k = 0; k <= l1 + l2 - l; k++) {
            int d0 = k, d1 = l1 + l2 - l - k, d2 = l1 - m1 - k;
            int d3 = l2 + m2 - k, d4 = l - l2 + m1 + k, d5 = l - l1 - m2 + k;
            if (d0 < 0 || d1 < 0 || d2 < 0 || d3 < 0 || d4 < 0 || d5 < 0) continue;
            double den = dfact(d0) * dfact(d1) * dfact(d2) * dfact(d3) * dfact(d4) * dfact(d5);
            s += ((k & 1) ? -1.0 : 1.0) / den;
        }
        v = (float)(pre * s);
    }
    cg[i] = v;
}

// ------------------------------------------------------- weight / std fold --
__global__ void w_init(const float2* __restrict__ w,
                       const float* __restrict__ stdv,
                       float2* __restrict__ wp) {
    int i = blockIdx.x * 256 + threadIdx.x;
    if (i >= WLEN) return;
    int l = 0;
    for (int k = 1; k < NL; k++) if (MT.w_off[k] <= i) l = k;
    int rel = i - MT.w_off[l];
    int T = rel % MT.mid_tau[l];
    float inv = 1.0f / (stdv[MT.std_off[l] + T] + 1e-5f);
    float2 wv = w[i];
    wp[i] = make_float2(wv.x * inv, wv.y * inv);
}

// ------------------------------------------------------------- main kernel --
template <int L>
__device__ __forceinline__ void process_l(int b, int tid,
                                          const float2* __restrict__ F,
                                          float2* __restrict__ mid,
                                          const float* __restrict__ cg,
                                          const float2* __restrict__ wp,
                                          float2* __restrict__ out) {
    constexpr int TW  = 2 * L + 1;
    constexpr int NCH = MT.nch[L];
    constexpr int NT  = MT.mid_tau[L];

    const int wid  = tid >> 6;     // wave 0..3
    const int lane = tid & 63;     // ts: (t,s)
    const int t = lane >> 3, s = lane & 7;
    const int g  = tid >> 5;       // output channel o (8 groups)
    const int hl = tid & 31;       // half-wave lane

    float2 acc[TW];
#pragma unroll
    for (int i = 0; i < TW; i++) acc[i] = make_float2(0.f, 0.f);

    static_for<NCH>([&](auto CHc) {
        constexpr int CH  = decltype(CHc)::value;
        constexpr int S0  = MT.ch_start[L][CH];
        constexpr int CNT = MT.ch_cnt[L][CH];
        constexpr int CT  = CNT * 64;            // T extent of this chunk
        static_assert(CT * TW <= MID_LDS, "chunk fits");

        __syncthreads();   // previous consumers of `mid` done (covers F load too)

        // ---- stage 1: mid[m][T] for slots [S0, S0+CNT) -------------------
        static_for<CNT>([&](auto SIc) {
            constexpr int SI   = S0 + decltype(SIc)::value;
            constexpr int TRIP = MT.trip_of_l[L][SI];
            constexpr int L1   = MT.tl1[TRIP];
            constexpr int L2v  = MT.tl2[TRIP];
            constexpr int N1   = 2 * L1 + 1, N2 = 2 * L2v + 1;
            if (MT.wave_of[L][SI] == wid) {
                const float2* F1 = F + MT.tf1[TRIP] + t * N1;
                const float2* F2 = F + MT.tf2[TRIP] + s * N2;
                float2 f1[N1], f2[N2];
#pragma unroll
                for (int i = 0; i < N1; i++) f1[i] = F1[i];
#pragma unroll
                for (int i = 0; i < N2; i++) f2[i] = F2[i];
                const int Tloc = (MT.ttloc[TRIP] - S0 * 64) + lane;
                static_for<TW>([&](auto MIc) {
                    constexpr int MI   = decltype(MIc)::value;
                    constexpr int BASE = MI - L;
                    constexpr int LO_  = BASE + L1 - L2v;
                    constexpr int LO   = LO_ < 0 ? 0 : LO_;
                    constexpr int HI_  = BASE + L1 + L2v;
                    constexpr int HI   = HI_ > 2 * L1 ? 2 * L1 : HI_;
                    float re = 0.f, im = 0.f;
                    static_for<HI - LO + 1>([&](auto Kc) {
                        constexpr int AI = LO + decltype(Kc)::value;
                        constexpr int CI = BASE + L1 + L2v - AI;
                        const float cv = cg[MT.tcg[TRIP] + MI * N1 * N2 + AI * N2 + CI];
                        const float2 a = f1[AI], c2 = f2[CI];
                        re = fmaf(cv, fmaf(-a.y, c2.y, a.x * c2.x), re);
                        im = fmaf(cv, fmaf(a.y, c2.x, a.x * c2.y), im);
                    });
                    mid[MI * CT + Tloc] = make_float2(re, im);
                });
            }
        });
        __syncthreads();

        // ---- stage 2: acc[o,m] += sum_T W'[o,T] * mid[m][T], 2 T's/iter --
        const float2* W = wp + MT.w_off[L] + g * NT + S0 * 64;
        for (int T = hl * 2; T < CT; T += 64) {
            const float4 wv = *reinterpret_cast<const float4*>(W + T);
#pragma unroll
            for (int mi = 0; mi < TW; mi++) {
                const float4 mv = *reinterpret_cast<const float4*>(mid + mi * CT + T);
                acc[mi].x = fmaf(wv.x, mv.x, fmaf(-wv.y, mv.y,
                             fmaf(wv.z, mv.z, fmaf(-wv.w, mv.w, acc[mi].x))));
                acc[mi].y = fmaf(wv.x, mv.y, fmaf(wv.y, mv.x,
                             fmaf(wv.z, mv.w, fmaf(wv.w, mv.z, acc[mi].y))));
            }
        }
    });

    // 32-lane reduction within each o-group
#pragma unroll
    for (int off = 16; off >= 1; off >>= 1) {
#pragma unroll
        for (int mi = 0; mi < TW; mi++) {
            acc[mi].x += __shfl_xor(acc[mi].x, off, 64);
            acc[mi].y += __shfl_xor(acc[mi].y, off, 64);
        }
    }
    if (hl == 0) {
        float2* orow = out + (size_t)b * ROW + MT.f_l[L] + g * TW;
#pragma unroll
        for (int mi = 0; mi < TW; mi++) orow[mi] = acc[mi];
    }
}

__global__ __launch_bounds__(256, 4) void fup_main(const float2* __restrict__ act,
                                                   const float* __restrict__ cg,
                                                   const float2* __restrict__ wp,
                                                   float2* __restrict__ out) {
    __shared__ float2 F[ROW];
    __shared__ __align__(16) float2 mid[MID_LDS];
    const int b = blockIdx.x;
    const int tid = threadIdx.x;
    const float2* arow = act + (size_t)b * ROW;
    for (int i = tid; i < ROW; i += 256) F[i] = arow[i];
    // sync happens at top of first chunk inside process_l<0>
    process_l<0>(b, tid, F, mid, cg, wp, out);
    process_l<1>(b, tid, F, mid, cg, wp, out);
    process_l<2>(b, tid, F, mid, cg, wp, out);
    process_l<3>(b, tid, F, mid, cg, wp, out);
    process_l<4>(b, tid, F, mid, cg, wp, out);
    process_l<5>(b, tid, F, mid, cg, wp, out);
}

// ----------------------------------------------------------------- launch ---
extern "C" void kernel_launch(void* const* d_in, const int* in_sizes, int n_in,
                              void* d_out, int out_size, void* d_ws, size_t ws_size,
                              hipStream_t stream) {
    const float2* act  = (const float2*)d_in[0];
    const float2* wts  = (const float2*)d_in[1];
    const float*  stdv = (const float*)d_in[2];
    float2* out = (float2*)d_out;

    float*  cg = (float*)d_ws;                                 // 24368 floats
    float2* wp = (float2*)((char*)d_ws + (size_t)24368 * 4);   // 35328 float2

    hipLaunchKernelGGL(cg_init, dim3((CG_TOTAL + 255) / 256), dim3(256), 0, stream, cg);
    hipLaunchKernelGGL(w_init,  dim3((WLEN + 255) / 256),     dim3(256), 0, stream,
                       wts, stdv, wp);
    hipLaunchKernelGGL(fup_main, dim3(BATCH), dim3(256), 0, stream, act, cg, wp, out);
}

// Round 4
// 115.200 us; speedup vs baseline: 2.3522x; 1.1965x over previous
//
#include <hip/hip_runtime.h>
#include <hip/hip_bf16.h>
#include <utility>

// fUpModule CG tensor product, MAXL=5, TAUS=OUT_TAUS=8, BATCH=1024, fp32 I/O.
// R4: CG coefficients fully constexpr (no cg table, no cg_init kernel);
// stage 2 uses 4 wave-groups x 2 output channels per mid read (halves LDS
// traffic vs R3's 8 half-wave groups); merge-shuffle reduction.

constexpr int NTRIP = 69;
constexpr int NL    = 6;
constexpr int BATCH = 1024;
constexpr int ROW   = 288;     // complex elements per activation/output row
constexpr int MID_LDS = 4224;  // float2 slots for mid buffer

struct Meta {
    int tl1[NTRIP], tl2[NTRIP], tll[NTRIP];
    int tf1[NTRIP], tf2[NTRIP];   // complex offsets of F[l1], F[l2] blocks
    int ttloc[NTRIP];             // T start of this triple within its l group
    int trip_of_l[NL][16];
    int ntrips[NL];
    int mid_tau[NL], std_off[NL], w_off[NL], f_l[NL];
    int nch[NL];
    int ch_start[NL][2], ch_cnt[NL][2];
    int wave_of[NL][16];
};

constexpr Meta build_meta() {
    Meta m{};
    int fl[NL] = {};
    {
        int acc = 0;
        for (int l = 0; l < NL; l++) { fl[l] = acc; m.f_l[l] = acc; acc += 8 * (2 * l + 1); }
    }
    int idx = 0;
    for (int l1 = 0; l1 <= 5; l1++)
        for (int l2 = 0; l2 <= l1; l2++) {
            int lmax = (l1 + l2 < 5) ? (l1 + l2) : 5;
            for (int l = l1 - l2; l <= lmax; l++) {
                m.tl1[idx] = l1; m.tl2[idx] = l2; m.tll[idx] = l;
                m.tf1[idx] = fl[l1]; m.tf2[idx] = fl[l2];
                m.ttloc[idx] = 64 * m.ntrips[l];
                m.trip_of_l[l][m.ntrips[l]] = idx;
                m.ntrips[l]++;
                idx++;
            }
        }
    int so = 0, wo = 0;
    for (int l = 0; l < NL; l++) {
        m.mid_tau[l] = 64 * m.ntrips[l];
        m.std_off[l] = so; so += m.mid_tau[l];
        m.w_off[l]   = wo; wo += 8 * m.mid_tau[l];
    }
    // chunking (balanced) + greedy cost-balanced slot->wave assignment
    for (int l = 0; l < NL; l++) {
        const int TW = 2 * l + 1;
        const int maxslot = MID_LDS / (64 * TW);
        const int ntl = m.ntrips[l];
        const int nch = (ntl + maxslot - 1) / maxslot;
        m.nch[l] = nch;
        int done = 0;
        for (int c = 0; c < nch; c++) {
            int cnt = (ntl - done + (nch - c) - 1) / (nch - c);
            m.ch_start[l][c] = done; m.ch_cnt[l][c] = cnt; done += cnt;
        }
        for (int c = 0; c < nch; c++) {
            const int s0 = m.ch_start[l][c], cnt = m.ch_cnt[l][c];
            int cost[16] = {}; bool asg[16] = {};
            for (int i = 0; i < cnt; i++) {
                int trip = m.trip_of_l[l][s0 + i];
                int l1 = m.tl1[trip], l2 = m.tl2[trip];
                int tc = 0;
                for (int mi = 0; mi < TW; mi++) {
                    int base = mi - l;
                    int lo = base + l1 - l2; if (lo < 0) lo = 0;
                    int hi = base + l1 + l2; if (hi > 2 * l1) hi = 2 * l1;
                    tc += hi - lo + 1;
                }
                cost[i] = tc * 6 + (2 * l1 + 1 + 2 * l2 + 1) * 2;
            }
            int load[4] = {};
            for (int k = 0; k < cnt; k++) {
                int best = -1, bc = -1;
                for (int i = 0; i < cnt; i++)
                    if (!asg[i] && cost[i] > bc) { bc = cost[i]; best = i; }
                asg[best] = true;
                int wsel = 0;
                for (int w2 = 1; w2 < 4; w2++) if (load[w2] < load[wsel]) wsel = w2;
                m.wave_of[l][s0 + best] = wsel;
                load[wsel] += bc;
            }
        }
    }
    return m;
}

constexpr Meta MT = build_meta();
constexpr int WLEN = 35328;  // complex weights
static_assert(MT.w_off[5] + 8 * MT.mid_tau[5] == WLEN, "wlen");
static_assert(MT.std_off[5] + MT.mid_tau[5] == 4416, "stdlen");

// ---------------------------------------------------- constexpr CG coeffs ---
constexpr double cfact(int n) {
    double r = 1.0;
    for (int i = 2; i <= n; i++) r *= (double)i;
    return r;
}
constexpr double csqrt(double x) {
    double g = x > 1.0 ? x : 1.0;
    for (int i = 0; i < 100; i++) g = 0.5 * (g + x / g);
    return g;
}
constexpr float cg_coeff(int l1, int l2, int l, int m1, int m2, int m) {
    if (m1 + m2 != m) return 0.0f;
    double pre = csqrt((double)(2 * l + 1) * cfact(l + l1 - l2) * cfact(l - l1 + l2) *
                       cfact(l1 + l2 - l) / cfact(l1 + l2 + l + 1));
    pre *= csqrt(cfact(l + m) * cfact(l - m) * cfact(l1 - m1) * cfact(l1 + m1) *
                 cfact(l2 - m2) * cfact(l2 + m2));
    double s = 0.0;
    for (int k = 0; k <= l1 + l2 - l; k++) {
        int d0 = k, d1 = l1 + l2 - l - k, d2 = l1 - m1 - k;
        int d3 = l2 + m2 - k, d4 = l - l2 + m1 + k, d5 = l - l1 - m2 + k;
        if (d0 < 0 || d1 < 0 || d2 < 0 || d3 < 0 || d4 < 0 || d5 < 0) continue;
        double den = cfact(d0) * cfact(d1) * cfact(d2) * cfact(d3) * cfact(d4) * cfact(d5);
        s += ((k & 1) ? -1.0 : 1.0) / den;
    }
    return (float)(pre * s);
}

// compile-time for
template <int... Is, class F>
__device__ __forceinline__ void static_for_impl(std::integer_sequence<int, Is...>, F&& f) {
    (f(std::integral_constant<int, Is>{}), ...);
}
template <int N, class F>
__device__ __forceinline__ void static_for(F&& f) {
    static_for_impl(std::make_integer_sequence<int, N>{}, (F&&)f);
}

// ------------------------------------------------------- weight / std fold --
__global__ void w_init(const float2* __restrict__ w,
                       const float* __restrict__ stdv,
                       float2* __restrict__ wp) {
    int i = blockIdx.x * 256 + threadIdx.x;
    if (i >= WLEN) return;
    int l = 0;
    for (int k = 1; k < NL; k++) if (MT.w_off[k] <= i) l = k;
    int rel = i - MT.w_off[l];
    int T = rel % MT.mid_tau[l];
    float inv = 1.0f / (stdv[MT.std_off[l] + T] + 1e-5f);
    float2 wv = w[i];
    wp[i] = make_float2(wv.x * inv, wv.y * inv);
}

// ------------------------------------------------------------- main kernel --
template <int L>
__device__ __forceinline__ void process_l(int b, int tid,
                                          const float2* __restrict__ F,
                                          float2* __restrict__ mid,
                                          const float2* __restrict__ wp,
                                          float2* __restrict__ out) {
    constexpr int TW  = 2 * L + 1;
    constexpr int NCH = MT.nch[L];
    constexpr int NT  = MT.mid_tau[L];

    const int wid  = tid >> 6;     // wave 0..3
    const int lane = tid & 63;     // stage1: ts = (t,s); stage2: T-lane
    const int t = lane >> 3, s = lane & 7;

    float2 acc0[TW], acc1[TW];     // o = wid, o = wid + 4
#pragma unroll
    for (int i = 0; i < TW; i++) { acc0[i] = make_float2(0.f, 0.f); acc1[i] = make_float2(0.f, 0.f); }

    static_for<NCH>([&](auto CHc) {
        constexpr int CH  = decltype(CHc)::value;
        constexpr int S0  = MT.ch_start[L][CH];
        constexpr int CNT = MT.ch_cnt[L][CH];
        constexpr int CT  = CNT * 64;            // T extent of this chunk
        static_assert(CT * TW <= MID_LDS, "chunk fits");

        __syncthreads();   // previous consumers of `mid` done (covers F load too)

        // ---- stage 1: mid[m][T] for slots [S0, S0+CNT) -------------------
        static_for<CNT>([&](auto SIc) {
            constexpr int SI   = S0 + decltype(SIc)::value;
            constexpr int TRIP = MT.trip_of_l[L][SI];
            constexpr int L1   = MT.tl1[TRIP];
            constexpr int L2v  = MT.tl2[TRIP];
            constexpr int N1   = 2 * L1 + 1, N2 = 2 * L2v + 1;
            if (MT.wave_of[L][SI] == wid) {
                const float2* F1 = F + MT.tf1[TRIP] + t * N1;
                const float2* F2 = F + MT.tf2[TRIP] + s * N2;
                float2 f1[N1], f2[N2];
#pragma unroll
                for (int i = 0; i < N1; i++) f1[i] = F1[i];
#pragma unroll
                for (int i = 0; i < N2; i++) f2[i] = F2[i];
                const int Tloc = (MT.ttloc[TRIP] - S0 * 64) + lane;
                static_for<TW>([&](auto MIc) {
                    constexpr int MI   = decltype(MIc)::value;
                    constexpr int BASE = MI - L;   // m
                    constexpr int LO_  = BASE + L1 - L2v;
                    constexpr int LO   = LO_ < 0 ? 0 : LO_;
                    constexpr int HI_  = BASE + L1 + L2v;
                    constexpr int HI   = HI_ > 2 * L1 ? 2 * L1 : HI_;
                    float re = 0.f, im = 0.f;
                    static_for<HI - LO + 1>([&](auto Kc) {
                        constexpr int AI = LO + decltype(Kc)::value;
                        constexpr int CI = BASE + L1 + L2v - AI;
                        constexpr float cv = cg_coeff(L1, L2v, L, AI - L1, CI - L2v, BASE);
                        if constexpr (cv != 0.0f) {
                            const float2 a = f1[AI], c2 = f2[CI];
                            re = fmaf(cv, fmaf(-a.y, c2.y, a.x * c2.x), re);
                            im = fmaf(cv, fmaf(a.y, c2.x, a.x * c2.y), im);
                        }
                    });
                    mid[MI * CT + Tloc] = make_float2(re, im);
                });
            }
        });
        __syncthreads();

        // ---- stage 2: acc[o,m] += sum_T W'[o,T]*mid[m][T]; 2 o's, 2 T's --
        const float2* W0 = wp + MT.w_off[L] + wid * NT + S0 * 64;
        const float2* W1 = wp + MT.w_off[L] + (wid + 4) * NT + S0 * 64;
        for (int T = lane * 2; T < CT; T += 128) {
            const float4 w0 = *reinterpret_cast<const float4*>(W0 + T);
            const float4 w1 = *reinterpret_cast<const float4*>(W1 + T);
#pragma unroll
            for (int mi = 0; mi < TW; mi++) {
                const float4 mv = *reinterpret_cast<const float4*>(mid + mi * CT + T);
                acc0[mi].x = fmaf(w0.x, mv.x, fmaf(-w0.y, mv.y,
                              fmaf(w0.z, mv.z, fmaf(-w0.w, mv.w, acc0[mi].x))));
                acc0[mi].y = fmaf(w0.x, mv.y, fmaf(w0.y, mv.x,
                              fmaf(w0.z, mv.w, fmaf(w0.w, mv.z, acc0[mi].y))));
                acc1[mi].x = fmaf(w1.x, mv.x, fmaf(-w1.y, mv.y,
                              fmaf(w1.z, mv.z, fmaf(-w1.w, mv.w, acc1[mi].x))));
                acc1[mi].y = fmaf(w1.x, mv.y, fmaf(w1.y, mv.x,
                              fmaf(w1.z, mv.w, fmaf(w1.w, mv.z, acc1[mi].y))));
            }
        }
    });

    // merge-reduce: lo half ends with sum for o=wid, hi half for o=wid+4
    const bool lo = (lane < 32);
    float2 red[TW];
#pragma unroll
    for (int mi = 0; mi < TW; mi++) {
        float gx = lo ? acc1[mi].x : acc0[mi].x;   // value to give away
        float gy = lo ? acc1[mi].y : acc0[mi].y;
        float rx = (lo ? acc0[mi].x : acc1[mi].x) + __shfl_xor(gx, 32, 64);
        float ry = (lo ? acc0[mi].y : acc1[mi].y) + __shfl_xor(gy, 32, 64);
#pragma unroll
        for (int off = 16; off >= 1; off >>= 1) {
            rx += __shfl_xor(rx, off, 64);
            ry += __shfl_xor(ry, off, 64);
        }
        red[mi] = make_float2(rx, ry);
    }
    if (lane == 0 || lane == 32) {
        const int o = wid + (lo ? 0 : 4);
        float2* orow = out + (size_t)b * ROW + MT.f_l[L] + o * TW;
#pragma unroll
        for (int mi = 0; mi < TW; mi++) orow[mi] = red[mi];
    }
}

__global__ __launch_bounds__(256, 4) void fup_main(const float2* __restrict__ act,
                                                   const float2* __restrict__ wp,
                                                   float2* __restrict__ out) {
    __shared__ float2 F[ROW];
    __shared__ __align__(16) float2 mid[MID_LDS];
    const int b = blockIdx.x;
    const int tid = threadIdx.x;
    const float2* arow = act + (size_t)b * ROW;
    for (int i = tid; i < ROW; i += 256) F[i] = arow[i];
    // sync happens at top of first chunk inside process_l<0>
    process_l<0>(b, tid, F, mid, wp, out);
    process_l<1>(b, tid, F, mid, wp, out);
    process_l<2>(b, tid, F, mid, wp, out);
    process_l<3>(b, tid, F, mid, wp, out);
    process_l<4>(b, tid, F, mid, wp, out);
    process_l<5>(b, tid, F, mid, wp, out);
}

// ----------------------------------------------------------------- launch ---
extern "C" void kernel_launch(void* const* d_in, const int* in_sizes, int n_in,
                              void* d_out, int out_size, void* d_ws, size_t ws_size,
                              hipStream_t stream) {
    const float2* act  = (const float2*)d_in[0];
    const float2* wts  = (const float2*)d_in[1];
    const float*  stdv = (const float*)d_in[2];
    float2* out = (float2*)d_out;

    float2* wp = (float2*)d_ws;   // 35328 float2 = 282 KB

    hipLaunchKernelGGL(w_init, dim3((WLEN + 255) / 256), dim3(256), 0, stream,
                       wts, stdv, wp);
    hipLaunchKernelGGL(fup_main, dim3(BATCH), dim3(256), 0, stream, act, wp, out);
}